// Round 5
// baseline (150.679 us; speedup 1.0000x reference)
//
#include <hip/hip_runtime.h>
#include <math.h>

// Problem constants (fixed by setup_inputs: B=32, C=2, H=512, W=512, fp32)
constexpr int Wd      = 512;
constexpr int Hd      = 512;
constexpr int HW      = Wd * Hd;        // 262144 elements per (b,c)
constexpr int NBC     = 64;             // B*C
constexpr int SPLITS  = 32;             // chunks per (b,c)
constexpr int CHUNK   = HW / SPLITS;    // 8192 elements per chunk (32 KB)
constexpr int NPART   = NBC * SPLITS;   // 2048 partials per role
constexpr int THREADS = 256;

typedef float f32x4 __attribute__((ext_vector_type(4)));
typedef __attribute__((address_space(3))) void       lds_vp;
typedef const __attribute__((address_space(1))) void gbl_vp;

// Workspace layout (floats): Pl[2048] Px[2048] Py[2048] Pv[2048] Pi[2048]
//
// R5: steady-state ring pipeline. R0-R4 all pinned at 3.15 TB/s reads
// regardless of structure; discriminating test between "read ceiling" and
// "average in-flight bytes too low". Each wave owns a 16KB LDS ring
// (16 x 1KB lines) and streams 64 lines (32KB input moments + 32KB target
// argmax): issue 16, then {vmcnt(15); ds_read line; lgkmcnt(0); reissue slot;
// compute}. Outstanding stays pinned at 16KB/wave (128KB/CU with 8 waves/CU)
// for the whole kernel - no phases, no barriers, both tensors per wave.
// Per-wave partials (w = bid*4+wave == bc*32+split) keep pass2 unchanged.

__global__ __launch_bounds__(THREADS) void dsnt_pass1(
    const float* __restrict__ inp, const float* __restrict__ tgt,
    float* __restrict__ ws) {
  __shared__ alignas(16) char smem[65536];   // 4 waves x 16 KB ring

  const int t    = threadIdx.x;
  const int wave = t >> 6;
  const int lane = t & 63;
  const int w     = (blockIdx.x << 2) | wave;   // 0..2047 wave-task id
  const int bc    = w >> 5;
  const int split = w & (SPLITS - 1);
  const int rbase = split * CHUNK;

  const char* gin = (const char*)(inp + (size_t)bc * HW + (size_t)rbase);
  const char* gtg = (const char*)(tgt + (size_t)bc * HW + (size_t)rbase);
  char* ring = smem + (wave << 14);             // wave-uniform 16 KB slice

  float* Pl = ws;
  float* Px = ws + NPART;
  float* Py = ws + 2 * NPART;
  float* Pv = ws + 3 * NPART;
  int*   Pi = (int*)(ws + 4 * NPART);

  // ---- prologue: fill the 16-slot ring (lines 0..15, all input) ----
#pragma unroll
  for (int j = 0; j < 16; ++j) {
    __builtin_amdgcn_global_load_lds(
        (gbl_vp*)(gin + j * 1024 + lane * 16),
        (lds_vp*)(ring + ((j & 15) << 10)), 16, 0, 0);
  }

  float lA = 0.f, lB = 0.f, sxA = 0.f, sxB = 0.f, syA = 0.f, syB = 0.f;
  float tvA = -INFINITY, tvB = -INFINITY;
  int   tiA = 0, tiB = 0;

  const f32x4* rp = (const f32x4*)ring;

  // ---- steady state: k = 0..47 consume line k, refill with line k+16 ----
#pragma unroll
  for (int k = 0; k < 48; ++k) {
    asm volatile("s_waitcnt vmcnt(15)" ::: "memory");   // oldest line landed
    __builtin_amdgcn_sched_barrier(0);
    const f32x4 v = rp[((k & 15) << 6) + lane];         // ds_read_b128 the line
    asm volatile("s_waitcnt lgkmcnt(0)" ::: "memory");  // slot consumed...
    __builtin_amdgcn_sched_barrier(0);
    {                                                   // ...so reuse is safe
      const int j = k + 16;                             // 16..63
      const char* g = (j < 32) ? (gin + j * 1024) : (gtg + (j - 32) * 1024);
      __builtin_amdgcn_global_load_lds(
          (gbl_vp*)(g + lane * 16),
          (lds_vp*)(ring + ((j & 15) << 10)), 16, 0, 0);
    }
    if (k < 32) {
      // input line: softmax moments (256 elems/line, 4 per lane)
      const int r = rbase + (k << 8) + (lane << 2);     // 4-aligned, same row
      const float yc = (float)((r >> 9) + 1);
      const float x0 = (float)((r & 511) + 1);
      const float e0 = __expf(v[0]);
      const float e1 = __expf(v[1]);
      const float e2 = __expf(v[2]);
      const float e3 = __expf(v[3]);
      lA += e0 + e2;
      lB += e1 + e3;
      sxA = fmaf(e0, x0,       sxA);  sxA = fmaf(e2, x0 + 2.f, sxA);
      sxB = fmaf(e1, x0 + 1.f, sxB);  sxB = fmaf(e3, x0 + 3.f, sxB);
      syA = fmaf(e0 + e2, yc, syA);
      syB = fmaf(e1 + e3, yc, syB);
    } else {
      // target line: argmax (two chains, per-chain indices strictly increase)
      const int r = rbase + ((k - 32) << 8) + (lane << 2);
      if (v[0] > tvA) { tvA = v[0]; tiA = r; }
      if (v[2] > tvA) { tvA = v[2]; tiA = r + 2; }
      if (v[1] > tvB) { tvB = v[1]; tiB = r + 1; }
      if (v[3] > tvB) { tvB = v[3]; tiB = r + 3; }
    }
  }

  // ---- tail: k = 48..63 (target lines), no refill ----
  asm volatile("s_waitcnt vmcnt(8)" ::: "memory");
  __builtin_amdgcn_sched_barrier(0);
#pragma unroll
  for (int k = 48; k < 56; ++k) {
    const f32x4 v = rp[((k & 15) << 6) + lane];
    const int r = rbase + ((k - 32) << 8) + (lane << 2);
    if (v[0] > tvA) { tvA = v[0]; tiA = r; }
    if (v[2] > tvA) { tvA = v[2]; tiA = r + 2; }
    if (v[1] > tvB) { tvB = v[1]; tiB = r + 1; }
    if (v[3] > tvB) { tvB = v[3]; tiB = r + 3; }
  }
  asm volatile("s_waitcnt vmcnt(0)" ::: "memory");
  __builtin_amdgcn_sched_barrier(0);
#pragma unroll
  for (int k = 56; k < 64; ++k) {
    const f32x4 v = rp[((k & 15) << 6) + lane];
    const int r = rbase + ((k - 32) << 8) + (lane << 2);
    if (v[0] > tvA) { tvA = v[0]; tiA = r; }
    if (v[2] > tvA) { tvA = v[2]; tiA = r + 2; }
    if (v[1] > tvB) { tvB = v[1]; tiB = r + 1; }
    if (v[3] > tvB) { tvB = v[3]; tiB = r + 3; }
  }

  // ---- wave-level reduction, per-wave partial writes (no barriers) ----
  float l = lA + lB, sx = sxA + sxB, sy = syA + syB;
  float tv = tvA; int ti = tiA;
  if (tvB > tv || (tvB == tv && tiB < ti)) { tv = tvB; ti = tiB; }

#pragma unroll
  for (int off = 32; off; off >>= 1) {
    l  += __shfl_xor(l, off);
    sx += __shfl_xor(sx, off);
    sy += __shfl_xor(sy, off);
    const float tv2 = __shfl_xor(tv, off);
    const int   ti2 = __shfl_xor(ti, off);
    if (tv2 > tv || (tv2 == tv && ti2 < ti)) { tv = tv2; ti = ti2; }
  }
  if (lane == 0) {
    Pl[w] = l; Px[w] = sx; Py[w] = sy;
    Pv[w] = tv; Pi[w] = ti;
  }
}

// Pass 2: one block, 256 threads. 4 threads per (b,c) each merge 8 partials,
// shfl-merge the 4, then a 64-lane butterfly produces the 3 scalar outputs.
__global__ __launch_bounds__(256) void dsnt_pass2(const float* __restrict__ ws,
                                                  float* __restrict__ out) {
  const int t    = threadIdx.x;
  const int bc   = t >> 2;      // 0..63 == b*2 + c
  const int part = t & 3;
  const float* Pl = ws;
  const float* Px = ws + NPART;
  const float* Py = ws + 2 * NPART;
  const float* Pv = ws + 3 * NPART;
  const int*   Pi = (const int*)(ws + 4 * NPART);

  float l = 0.f, sx = 0.f, sy = 0.f;
  float tv = -INFINITY;
  int   ti = 0x7fffffff;
#pragma unroll
  for (int j = 0; j < 8; ++j) {
    const int p = bc * SPLITS + part * 8 + j;
    l  += Pl[p];
    sx += Px[p];
    sy += Py[p];
    const float v  = Pv[p];
    const int   ix = Pi[p];
    if (v > tv || (v == tv && ix < ti)) { tv = v; ti = ix; }
  }
#pragma unroll
  for (int off = 1; off <= 2; off <<= 1) {
    l  += __shfl_xor(l, off);
    sx += __shfl_xor(sx, off);
    sy += __shfl_xor(sy, off);
    const float tv2 = __shfl_xor(tv, off);
    const int   ti2 = __shfl_xor(ti, off);
    if (tv2 > tv || (tv2 == tv && ti2 < ti)) { tv = tv2; ti = ti2; }
  }

  __shared__ float edArr[NBC];
  if (part == 0) {
    const float predx = sx / l;
    const float predy = sy / l;
    const float truex = (float)((ti & 511) + 1);
    const float truey = (float)((ti >> 9) + 1);
    const float dx = truex - predx, dy = truey - predy;
    edArr[bc] = sqrtf(dx * dx + dy * dy);
  }
  __syncthreads();
  if (t < NBC) {
    const float ed = edArr[t];
    float ei = (t & 1) ? 0.f : ed;   // channel 0 (even bc) -> inferior
    float es = (t & 1) ? ed : 0.f;   // channels >=1        -> superior
#pragma unroll
    for (int off = 32; off; off >>= 1) {
      ei += __shfl_xor(ei, off);
      es += __shfl_xor(es, off);
    }
    if (t == 0) {
      out[0] = ei * (1.f / 32.f);          // s_i / B
      out[1] = es * (1.f / 32.f);          // s_s / B
      out[2] = (ei + es) * (1.f / 32.f);   // (s_i+s_s) / B
    }
  }
}

extern "C" void kernel_launch(void* const* d_in, const int* in_sizes, int n_in,
                              void* d_out, int out_size, void* d_ws, size_t ws_size,
                              hipStream_t stream) {
  const float* inp = (const float*)d_in[0];
  const float* tgt = (const float*)d_in[1];
  float* out = (float*)d_out;
  float* ws  = (float*)d_ws;   // needs 5 * 2048 * 4 B = 40 KiB

  dsnt_pass1<<<NPART / 4, THREADS, 0, stream>>>(inp, tgt, ws);
  dsnt_pass2<<<1, 256, 0, stream>>>(ws, out);
}